// Round 1
// 7422.252 us; speedup vs baseline: 1.7190x; 1.7190x over previous
//
#include <hip/hip_runtime.h>
#include <math.h>

// Problem dims (fixed by reference)
constexpr int NL = 4, D = 1024, NH = 16, DH = 64, DFF = 4096, NV = 8192;
constexpr int NB = 4, NQ = 512, NM = 512, NE = 512, KLEN = 1024; // KLEN = NM+NQ

using frag16 = __attribute__((ext_vector_type(8))) short;  // 8 bf16 = 4 VGPR
using f32x4  = __attribute__((ext_vector_type(4))) float;  // MFMA acc

// ---------------------------------------------------------------------------
// Embedding lookup: x[b,q,:] = emb[id] * sqrt(D) (=32)
__global__ __launch_bounds__(256) void k_embed(const float* __restrict__ emb,
                                               const int* __restrict__ ids,
                                               float* __restrict__ x) {
  int row = blockIdx.x;                 // 0..NB*NQ-1
  int id = ids[row];
  const float4* src = (const float4*)(emb + (size_t)id * D);
  float4* dst = (float4*)(x + (size_t)row * D);
  for (int i = threadIdx.x; i < D / 4; i += 256) {
    float4 t = src[i];
    t.x *= 32.f; t.y *= 32.f; t.z *= 32.f; t.w *= 32.f;
    dst[i] = t;
  }
}

// ---------------------------------------------------------------------------
// Relative positional embedding r_emb[p, d]
__global__ __launch_bounds__(256) void k_posemb(float* __restrict__ r_emb) {
  int p = blockIdx.x;
  float pos = (float)(KLEN - 1 - p);
  for (int d = threadIdx.x; d < D; d += 256) {
    int i = (d < D / 2) ? d : d - D / 2;
    float freq = (float)pow(10000.0, -(double)(2 * i) / (double)D);
    float a = pos * freq;
    r_emb[(size_t)p * D + d] = (d < D / 2) ? sinf(a) : cosf(a);
  }
}

// ---------------------------------------------------------------------------
// mem = concat(mems[l], x) along sequence
__global__ __launch_bounds__(256) void k_concat(const float* __restrict__ mems_l,
                                                const float* __restrict__ x,
                                                float* __restrict__ mem) {
  int row = blockIdx.x;                 // b*KLEN + t
  int b = row / KLEN, t = row % KLEN;
  const float4* src = (const float4*)((t < NM)
      ? (mems_l + ((size_t)b * NM + t) * D)
      : (x + ((size_t)b * NQ + (t - NM)) * D));
  float4* dst = (float4*)(mem + (size_t)row * D);
  for (int i = threadIdx.x; i < D / 4; i += 256) dst[i] = src[i];
}

// ---------------------------------------------------------------------------
// bf16 hi/lo split helpers (RNE). x == hi + lo to ~2^-17 rel; AlBl term dropped
// in the GEMM contributes <= 2^-18 rel => fp32-equivalent product accuracy.
__device__ inline void split2(float x, unsigned short& h, unsigned short& lo) {
  unsigned u = __float_as_uint(x);
  unsigned hr = (u + 0x7FFFu + ((u >> 16) & 1u)) & 0xFFFF0000u;
  h = (unsigned short)(hr >> 16);
  float r = x - __uint_as_float(hr);
  unsigned ur = __float_as_uint(r);
  lo = (unsigned short)((ur + 0x7FFFu + ((ur >> 16) & 1u)) >> 16);
}

// Elementwise split: A[n] fp32 -> H[n], L[n] bf16 (same layout, K-contiguous)
__global__ __launch_bounds__(256) void k_split4(const float* __restrict__ A,
                                                unsigned short* __restrict__ H,
                                                unsigned short* __restrict__ L,
                                                int n4) {
  int i = blockIdx.x * 256 + threadIdx.x;
  if (i >= n4) return;
  float4 f = ((const float4*)A)[i];
  ushort4 h, lo;
  split2(f.x, h.x, lo.x);
  split2(f.y, h.y, lo.y);
  split2(f.z, h.z, lo.z);
  split2(f.w, h.w, lo.w);
  ((ushort4*)H)[i] = h;
  ((ushort4*)L)[i] = lo;
}

// Transpose-split: W[K][N] fp32 -> H,L [N][K] bf16 (MFMA B-operand wants
// K-contiguous per output column). 32x32 LDS tile keeps both sides coalesced.
__global__ __launch_bounds__(256) void k_split_t(const float* __restrict__ W,
                                                 unsigned short* __restrict__ H,
                                                 unsigned short* __restrict__ L,
                                                 int K, int N) {
  __shared__ float t[32][33];
  int n0 = blockIdx.x * 32, k0 = blockIdx.y * 32;
  int tx = threadIdx.x & 31, ty = threadIdx.x >> 5;  // ty 0..7
#pragma unroll
  for (int i = 0; i < 4; ++i)
    t[ty + 8 * i][tx] = W[(size_t)(k0 + ty + 8 * i) * N + n0 + tx];
  __syncthreads();
#pragma unroll
  for (int i = 0; i < 4; ++i) {
    int n = n0 + ty + 8 * i, k = k0 + tx;
    unsigned short h, lo;
    split2(t[tx][ty + 8 * i], h, lo);
    H[(size_t)n * K + k] = h;
    L[(size_t)n * K + k] = lo;
  }
}

// ---------------------------------------------------------------------------
// bf16x3 MFMA GEMM: C[M][N] = (Ah+Al)[M][K] @ (Bh+Bl)[N][K]^T  (fp32 out)
// C = Ah.Bh + Ah.Bl + Al.Bh (AlBl dropped). BM=128, BK=32, BN template (128/64).
// 256 thr = 4 waves (2x2); wave tile 64 x BN/2; mfma_f32_16x16x32_bf16.
// Staging: global_load_lds width-16, linear LDS dest, inverse-swizzled global
// source granule (g ^ ((row>>1)&3)) -> 2-way-max bank aliasing on ds_read_b128
// (free per m136). m97 2-phase: prefetch next K-tile, compute, one barrier.
template <int BN>
__global__ __launch_bounds__(256, 2) void k_mgemm(
    const unsigned short* __restrict__ Ah, const unsigned short* __restrict__ Al,
    const unsigned short* __restrict__ Bh, const unsigned short* __restrict__ Bl,
    float* __restrict__ C, int Mdim, int Ndim, int Kdim) {
  constexpr int NI = BN / 32;        // B-frags per wave (4 or 2)
  constexpr int WCN = BN / 2;        // wave N extent
  constexpr int NCB = BN / 16;       // 16-row chunks per B plane
  constexpr int NC = 16 + 2 * NCB;   // total staging chunks per K-tile
  constexpr int PA = 128 * 32;       // plane size (ushorts)
  constexpr int PB = BN * 32;
  constexpr int BUF = 2 * PA + 2 * PB;
  __shared__ __align__(16) unsigned short lds[2][BUF];

  const int tid = threadIdx.x;
  const int l = tid & 63, w = tid >> 6;
  const int wr = w >> 1, wc = w & 1;
  const int lr = l & 15, lg = l >> 4;
  const int m0 = blockIdx.y * 128, n0 = blockIdx.x * BN;
  // staging lane decode: lane covers row sr (64B), granule sg (16B)
  const int sr = l >> 2, sg = l & 3;
  const int sgs = (sg ^ ((sr >> 1) & 3)) * 8;   // swizzled source granule (ushorts)
  // fragment-read swizzle (row within 16-row chunk is lr)
  const int glo = (lg ^ ((lr >> 1) & 3)) * 8;

  f32x4 acc[4][NI];
#pragma unroll
  for (int i = 0; i < 4; ++i)
#pragma unroll
    for (int j = 0; j < NI; ++j)
      acc[i][j] = (f32x4){0.f, 0.f, 0.f, 0.f};

  auto stage = [&](int bb, int kt) {
    for (int cid = w; cid < NC; cid += 4) {
      const unsigned short* gb;
      int ldso;
      if (cid < 8) {
        gb = Ah + (size_t)(m0 + cid * 16 + sr) * Kdim;
        ldso = cid * 16 * 32;
      } else if (cid < 16) {
        gb = Al + (size_t)(m0 + (cid - 8) * 16 + sr) * Kdim;
        ldso = PA + (cid - 8) * 16 * 32;
      } else if (cid < 16 + NCB) {
        gb = Bh + (size_t)(n0 + (cid - 16) * 16 + sr) * Kdim;
        ldso = 2 * PA + (cid - 16) * 16 * 32;
      } else {
        gb = Bl + (size_t)(n0 + (cid - 16 - NCB) * 16 + sr) * Kdim;
        ldso = 2 * PA + PB + (cid - 16 - NCB) * 16 * 32;
      }
      const unsigned short* src = gb + kt + sgs;
      __builtin_amdgcn_global_load_lds(
          (const __attribute__((address_space(1))) void*)src,
          (__attribute__((address_space(3))) void*)&lds[bb][ldso], 16, 0, 0);
    }
  };

  auto comp = [&](int bb) {
    frag16 af[4], alf[4], bf[NI], blf[NI];
#pragma unroll
    for (int mi = 0; mi < 4; ++mi) {
      int ro = (wr * 64 + mi * 16 + lr) * 32 + glo;
      af[mi]  = *(const frag16*)&lds[bb][ro];
      alf[mi] = *(const frag16*)&lds[bb][PA + ro];
    }
#pragma unroll
    for (int ni = 0; ni < NI; ++ni) {
      int ro = (wc * WCN + ni * 16 + lr) * 32 + glo;
      bf[ni]  = *(const frag16*)&lds[bb][2 * PA + ro];
      blf[ni] = *(const frag16*)&lds[bb][2 * PA + PB + ro];
    }
#pragma unroll
    for (int mi = 0; mi < 4; ++mi)
#pragma unroll
      for (int ni = 0; ni < NI; ++ni) {
        acc[mi][ni] = __builtin_amdgcn_mfma_f32_16x16x32_bf16(af[mi], bf[ni], acc[mi][ni], 0, 0, 0);
        acc[mi][ni] = __builtin_amdgcn_mfma_f32_16x16x32_bf16(af[mi], blf[ni], acc[mi][ni], 0, 0, 0);
        acc[mi][ni] = __builtin_amdgcn_mfma_f32_16x16x32_bf16(alf[mi], bf[ni], acc[mi][ni], 0, 0, 0);
      }
  };

  const int NT = Kdim / 32;
  stage(0, 0);
  __syncthreads();                       // drains vmcnt(0): tile0 resident
  int bb = 0;
  for (int t = 0; t < NT; ++t) {
    if (t + 1 < NT) stage(bb ^ 1, (t + 1) * 32);  // prefetch flies under compute
    comp(bb);
    __syncthreads();                     // barrier + vmcnt drain: next tile ready
    bb ^= 1;
  }
  // Epilogue. C/D layout (m89-verified): col = lane&15, row = (lane>>4)*4 + reg.
#pragma unroll
  for (int mi = 0; mi < 4; ++mi)
#pragma unroll
    for (int ni = 0; ni < NI; ++ni) {
      int row = m0 + wr * 64 + mi * 16 + lg * 4;
      int col = n0 + wc * WCN + ni * 16 + lr;
#pragma unroll
      for (int j = 0; j < 4; ++j)
        C[(size_t)(row + j) * Ndim + col] = acc[mi][ni][j];
    }
}

// ---------------------------------------------------------------------------
// fp32 SGEMM (fallback path only): C[M,N] = A[M,K] @ B[K,N]. 128x128, BK=16.
__global__ __launch_bounds__(256) void k_gemm(const float* __restrict__ A,
                                              const float* __restrict__ Bm,
                                              float* __restrict__ C,
                                              int Md, int Nd, int Kd) {
  __shared__ float As[16][132];   // [k][m]
  __shared__ float Bs[16][128];   // [k][n]
  int tid = threadIdx.x;
  int tx = tid & 15, ty = tid >> 4;
  int m0 = blockIdx.y * 128, n0 = blockIdx.x * 128;
  float acc[8][8] = {{0.f}};
  for (int k0 = 0; k0 < Kd; k0 += 16) {
#pragma unroll
    for (int ld = 0; ld < 2; ++ld) {
      int idx = tid + ld * 256;
      int row = idx >> 2, kq = idx & 3;
      float4 t = *(const float4*)(A + (size_t)(m0 + row) * Kd + k0 + kq * 4);
      As[kq * 4 + 0][row] = t.x;
      As[kq * 4 + 1][row] = t.y;
      As[kq * 4 + 2][row] = t.z;
      As[kq * 4 + 3][row] = t.w;
      int kk2 = idx >> 5, nq = idx & 31;
      *(float4*)&Bs[kk2][nq * 4] = *(const float4*)(Bm + (size_t)(k0 + kk2) * Nd + n0 + nq * 4);
    }
    __syncthreads();
#pragma unroll
    for (int kkk = 0; kkk < 16; ++kkk) {
      float a[8], bq[8];
      *(float4*)&a[0] = *(const float4*)&As[kkk][ty * 8];
      *(float4*)&a[4] = *(const float4*)&As[kkk][ty * 8 + 4];
      *(float4*)&bq[0] = *(const float4*)&Bs[kkk][tx * 8];
      *(float4*)&bq[4] = *(const float4*)&Bs[kkk][tx * 8 + 4];
#pragma unroll
      for (int i = 0; i < 8; ++i)
#pragma unroll
        for (int j = 0; j < 8; ++j)
          acc[i][j] = fmaf(a[i], bq[j], acc[i][j]);
    }
    __syncthreads();
  }
#pragma unroll
  for (int i = 0; i < 8; ++i) {
    float* cr = C + (size_t)(m0 + ty * 8 + i) * Nd + n0 + tx * 8;
    float4 o1 = {acc[i][0], acc[i][1], acc[i][2], acc[i][3]};
    float4 o2 = {acc[i][4], acc[i][5], acc[i][6], acc[i][7]};
    *(float4*)cr = o1;
    *(float4*)(cr + 4) = o2;
  }
}

// ---------------------------------------------------------------------------
// Score NT-GEMM over one (b): C[h][i][j] = sum_d (A[i][d]+bias[h][d]) * B[j][d]
template <bool SHIFT>
__global__ __launch_bounds__(256) void k_qkt(const float* __restrict__ A,
                                             const float* __restrict__ Bm,
                                             const float* __restrict__ bias,
                                             float* __restrict__ C,
                                             int cols) {
  __shared__ float As[16][132];
  __shared__ float Bs[16][132];
  int h = blockIdx.z;
  int m0 = blockIdx.y * 128, n0 = blockIdx.x * 128;
  const float* Ab = A + h * DH;
  const float* Bb = Bm + h * DH;
  float* Cb = C + (size_t)h * NQ * cols;
  int tid = threadIdx.x, tx = tid & 15, ty = tid >> 4;
  float acc[8][8] = {{0.f}};
  for (int k0 = 0; k0 < DH; k0 += 16) {
#pragma unroll
    for (int ld = 0; ld < 2; ++ld) {
      int idx = tid + ld * 256;
      int row = idx >> 2, kq = idx & 3;
      float4 t = *(const float4*)(Ab + (size_t)(m0 + row) * D + k0 + kq * 4);
      float4 bv = {0.f, 0.f, 0.f, 0.f};
      if (bias) bv = *(const float4*)(bias + h * DH + k0 + kq * 4);
      As[kq * 4 + 0][row] = t.x + bv.x;
      As[kq * 4 + 1][row] = t.y + bv.y;
      As[kq * 4 + 2][row] = t.z + bv.z;
      As[kq * 4 + 3][row] = t.w + bv.w;
      float4 tb = *(const float4*)(Bb + (size_t)(n0 + row) * D + k0 + kq * 4);
      Bs[kq * 4 + 0][row] = tb.x;
      Bs[kq * 4 + 1][row] = tb.y;
      Bs[kq * 4 + 2][row] = tb.z;
      Bs[kq * 4 + 3][row] = tb.w;
    }
    __syncthreads();
#pragma unroll
    for (int kkk = 0; kkk < 16; ++kkk) {
      float a[8], bq[8];
      *(float4*)&a[0] = *(const float4*)&As[kkk][ty * 8];
      *(float4*)&a[4] = *(const float4*)&As[kkk][ty * 8 + 4];
      *(float4*)&bq[0] = *(const float4*)&Bs[kkk][tx * 8];
      *(float4*)&bq[4] = *(const float4*)&Bs[kkk][tx * 8 + 4];
#pragma unroll
      for (int i = 0; i < 8; ++i)
#pragma unroll
        for (int j = 0; j < 8; ++j)
          acc[i][j] = fmaf(a[i], bq[j], acc[i][j]);
    }
    __syncthreads();
  }
  if (!SHIFT) {
#pragma unroll
    for (int i = 0; i < 8; ++i) {
      float* cr = Cb + (size_t)(m0 + ty * 8 + i) * cols + n0 + tx * 8;
      float4 o1 = {acc[i][0], acc[i][1], acc[i][2], acc[i][3]};
      float4 o2 = {acc[i][4], acc[i][5], acc[i][6], acc[i][7]};
      *(float4*)cr = o1;
      *(float4*)(cr + 4) = o2;
    }
  } else {
#pragma unroll
    for (int i = 0; i < 8; ++i) {
      int ig = m0 + ty * 8 + i;
      float* cr = Cb + (size_t)ig * cols;
#pragma unroll
      for (int j = 0; j < 8; ++j) {
        int p = n0 + tx * 8 + j;
        int jj = p - (NQ - 1) + ig;
        if (jj >= 0) cr[jj] += acc[i][j];
      }
    }
  }
}

// ---------------------------------------------------------------------------
// Row softmax over sc[h][i][0..KL): scale 0.125, (MASK) j>NM+i -> -inf
template <int KL, bool MASK>
__global__ __launch_bounds__(256) void k_softmax(float* __restrict__ sc) {
  int i = blockIdx.x, h = blockIdx.y, tid = threadIdx.x;
  float* r = sc + ((size_t)h * NQ + i) * KL;
  __shared__ float red[256];
  constexpr int NV4 = KL / 4;
  float4 v = {-1e30f, -1e30f, -1e30f, -1e30f};
  if (tid < NV4) {
    v = ((float4*)r)[tid];
    v.x *= 0.125f; v.y *= 0.125f; v.z *= 0.125f; v.w *= 0.125f;
    if (MASK) {
      int j = tid * 4;
      if (j + 0 > NM + i) v.x = -1e30f;
      if (j + 1 > NM + i) v.y = -1e30f;
      if (j + 2 > NM + i) v.z = -1e30f;
      if (j + 3 > NM + i) v.w = -1e30f;
    }
  }
  red[tid] = fmaxf(fmaxf(v.x, v.y), fmaxf(v.z, v.w));
  __syncthreads();
  for (int off = 128; off > 0; off >>= 1) {
    if (tid < off) red[tid] = fmaxf(red[tid], red[tid + off]);
    __syncthreads();
  }
  float gm = red[0];
  __syncthreads();
  float4 e = {0.f, 0.f, 0.f, 0.f};
  if (tid < NV4) {
    e.x = __expf(v.x - gm);
    e.y = __expf(v.y - gm);
    e.z = __expf(v.z - gm);
    e.w = __expf(v.w - gm);
  }
  red[tid] = e.x + e.y + e.z + e.w;
  __syncthreads();
  for (int off = 128; off > 0; off >>= 1) {
    if (tid < off) red[tid] += red[tid + off];
    __syncthreads();
  }
  float inv = 1.f / red[0];
  if (tid < NV4) {
    e.x *= inv; e.y *= inv; e.z *= inv; e.w *= inv;
    ((float4*)r)[tid] = e;
  }
}

// ---------------------------------------------------------------------------
// PV NN-GEMM per (b): av[i][h*DH+d] = sum_j P[h][i][j] * V[j][h*DH+d]
template <int KL>
__global__ __launch_bounds__(256) void k_pv(const float* __restrict__ sc,
                                            const float* __restrict__ V,
                                            float* __restrict__ av) {
  __shared__ float As[16][132];
  __shared__ float Bs[16][68];
  int h = blockIdx.y;
  int m0 = blockIdx.x * 128;
  const float* P = sc + (size_t)h * NQ * KL;
  const float* Vb = V + h * DH;
  int tid = threadIdx.x, tx = tid & 15, ty = tid >> 4;
  float acc[8][4] = {{0.f}};
  for (int k0 = 0; k0 < KL; k0 += 16) {
#pragma unroll
    for (int ld = 0; ld < 2; ++ld) {
      int idx = tid + ld * 256;
      int row = idx >> 2, kq = idx & 3;
      float4 t = *(const float4*)(P + (size_t)(m0 + row) * KL + k0 + kq * 4);
      As[kq * 4 + 0][row] = t.x;
      As[kq * 4 + 1][row] = t.y;
      As[kq * 4 + 2][row] = t.z;
      As[kq * 4 + 3][row] = t.w;
    }
    {
      int kk = tid >> 4, nq = tid & 15;
      *(float4*)&Bs[kk][nq * 4] = *(const float4*)(Vb + (size_t)(k0 + kk) * D + nq * 4);
    }
    __syncthreads();
#pragma unroll
    for (int kkk = 0; kkk < 16; ++kkk) {
      float a[8], bq[4];
      *(float4*)&a[0] = *(const float4*)&As[kkk][ty * 8];
      *(float4*)&a[4] = *(const float4*)&As[kkk][ty * 8 + 4];
      *(float4*)&bq[0] = *(const float4*)&Bs[kkk][tx * 4];
#pragma unroll
      for (int i = 0; i < 8; ++i)
#pragma unroll
        for (int j = 0; j < 4; ++j)
          acc[i][j] = fmaf(a[i], bq[j], acc[i][j]);
    }
    __syncthreads();
  }
#pragma unroll
  for (int i = 0; i < 8; ++i) {
    float4 o = {acc[i][0], acc[i][1], acc[i][2], acc[i][3]};
    *(float4*)(av + (size_t)(m0 + ty * 8 + i) * D + h * DH + tx * 4) = o;
  }
}

// ---------------------------------------------------------------------------
// x = LayerNorm(x + y + bias) * g + b   (in place on x; one block per row)
__global__ __launch_bounds__(256) void k_ln(float* __restrict__ x,
                                            const float* __restrict__ y,
                                            const float* __restrict__ bias,
                                            const float* __restrict__ g,
                                            const float* __restrict__ bb) {
  int row = blockIdx.x;
  int tid = threadIdx.x;
  __shared__ float red[256];
  size_t base = (size_t)row * D + tid * 4;
  float4 xv = *(const float4*)(x + base);
  float4 yv = *(const float4*)(y + base);
  float4 bv = *(const float4*)(bias + tid * 4);
  float v0 = xv.x + yv.x + bv.x;
  float v1 = xv.y + yv.y + bv.y;
  float v2 = xv.z + yv.z + bv.z;
  float v3 = xv.w + yv.w + bv.w;
  red[tid] = v0 + v1 + v2 + v3;
  __syncthreads();
  for (int off = 128; off > 0; off >>= 1) {
    if (tid < off) red[tid] += red[tid + off];
    __syncthreads();
  }
  float mu = red[0] * (1.f / D);
  __syncthreads();
  v0 -= mu; v1 -= mu; v2 -= mu; v3 -= mu;
  red[tid] = v0 * v0 + v1 * v1 + v2 * v2 + v3 * v3;
  __syncthreads();
  for (int off = 128; off > 0; off >>= 1) {
    if (tid < off) red[tid] += red[tid + off];
    __syncthreads();
  }
  float inv = rsqrtf(red[0] * (1.f / D) + 1e-5f);
  float4 gv = *(const float4*)(g + tid * 4);
  float4 bbv = *(const float4*)(bb + tid * 4);
  float4 o;
  o.x = v0 * inv * gv.x + bbv.x;
  o.y = v1 * inv * gv.y + bbv.y;
  o.z = v2 * inv * gv.z + bbv.z;
  o.w = v3 * inv * gv.w + bbv.w;
  *(float4*)(x + base) = o;
}

// ---------------------------------------------------------------------------
// h = gelu(h + b1), exact erf variant
__global__ __launch_bounds__(256) void k_bias_gelu(float* __restrict__ h,
                                                   const float* __restrict__ b1) {
  size_t idx = ((size_t)blockIdx.x * 256 + threadIdx.x) * 4;
  int col = (int)(idx % DFF);
  float4 t = *(float4*)(h + idx);
  float4 bv = *(const float4*)(b1 + col);
  float a0 = t.x + bv.x, a1 = t.y + bv.y, a2 = t.z + bv.z, a3 = t.w + bv.w;
  const float inv_sqrt2 = 0.70710678118654752f;
  t.x = 0.5f * a0 * (1.f + erff(a0 * inv_sqrt2));
  t.y = 0.5f * a1 * (1.f + erff(a1 * inv_sqrt2));
  t.z = 0.5f * a2 * (1.f + erff(a2 * inv_sqrt2));
  t.w = 0.5f * a3 * (1.f + erff(a3 * inv_sqrt2));
  *(float4*)(h + idx) = t;
}

// ---------------------------------------------------------------------------
extern "C" void kernel_launch(void* const* d_in, const int* in_sizes, int n_in,
                              void* d_out, int out_size, void* d_ws, size_t ws_size,
                              hipStream_t stream) {
  const float* enc    = (const float*)d_in[0];
  const float* mems   = (const float*)d_in[1];
  const float* emb    = (const float*)d_in[2];
  const float* u_b    = (const float*)d_in[3];
  const float* v_b    = (const float*)d_in[4];
  const float* sa_Wq  = (const float*)d_in[5];
  const float* sa_Wk  = (const float*)d_in[6];
  const float* sa_Wv  = (const float*)d_in[7];
  const float* sa_Wr  = (const float*)d_in[8];
  const float* sa_fcW = (const float*)d_in[9];
  const float* sa_fcB = (const float*)d_in[10];
  const float* ln1_g  = (const float*)d_in[11];
  const float* ln1_b  = (const float*)d_in[12];
  const float* ca_Wq  = (const float*)d_in[13];
  const float* ca_Wk  = (const float*)d_in[14];
  const float* ca_Wv  = (const float*)d_in[15];
  const float* ca_fcW = (const float*)d_in[16];
  const float* ca_fcB = (const float*)d_in[17];
  const float* ln2_g  = (const float*)d_in[18];
  const float* ln2_b  = (const float*)d_in[19];
  const float* ff_W1  = (const float*)d_in[20];
  const float* ff_b1  = (const float*)d_in[21];
  const float* ff_W2  = (const float*)d_in[22];
  const float* ff_b2  = (const float*)d_in[23];
  const float* ln3_g  = (const float*)d_in[24];
  const float* ln3_b  = (const float*)d_in[25];
  const float* out_W  = (const float*)d_in[26];
  const int*   ids    = (const int*)d_in[27];
  float* out = (float*)d_out;

  // --- Workspace layout ---
  // fp32 region (31,457,280 floats = 125,829,120 B):
  float* ws    = (float*)d_ws;
  float* r_emb = ws;                                  // 1M
  float* xb    = r_emb + (size_t)KLEN * D;            // 2M
  float* yb    = xb   + (size_t)NB * NQ * D;          // 2M
  float* avb   = yb   + (size_t)NB * NQ * D;          // 2M
  float* qb    = avb  + (size_t)NB * NQ * D;          // 2M
  float* memb  = qb   + (size_t)NB * NQ * D;          // 4M
  float* kb    = memb + (size_t)NB * KLEN * D;        // 4M
  float* vb    = kb   + (size_t)NB * KLEN * D;        // 4M
  float* rb    = vb   + (size_t)NB * KLEN * D;        // 1M
  float* scb   = rb   + (size_t)KLEN * D;             // 8M
  float* hff   = memb;  // FF hidden (8M floats) aliases memb+kb, dead during FF
  // bf16 split region (39,845,888 ushorts = 79,691,776 B):
  unsigned short* ah   = (unsigned short*)(scb + (size_t)NH * NQ * KLEN); // 8M
  unsigned short* al   = ah + (size_t)8 * 1024 * 1024;                    // 8M
  unsigned short* bh   = al + (size_t)8 * 1024 * 1024;                    // 8M
  unsigned short* bl   = bh + (size_t)8 * 1024 * 1024;                    // 8M
  unsigned short* ench = bl + (size_t)8 * 1024 * 1024;                    // 2M
  unsigned short* encl = ench + (size_t)NB * NE * D;                      // 2M
  unsigned short* rh   = encl + (size_t)NB * NE * D;                      // 1M
  unsigned short* rl   = rh + (size_t)KLEN * D;                           // 1M
  const size_t WS_NEEDED = 205520896ull;  // bytes

  if (ws_size < WS_NEEDED) {
    // ---------- Fallback: previous verified fp32 path (12.8 ms) ----------
    auto gemm = [&](const float* A, const float* Bp, float* C, int Md, int Nd, int Kd) {
      dim3 g(Nd / 128, Md / 128);
      k_gemm<<<g, 256, 0, stream>>>(A, Bp, C, Md, Nd, Kd);
    };
    k_embed<<<NB * NQ, 256, 0, stream>>>(emb, ids, xb);
    k_posemb<<<KLEN, 256, 0, stream>>>(r_emb);
    for (int l = 0; l < NL; ++l) {
      size_t wo = (size_t)l * D * D;
      k_concat<<<NB * KLEN, 256, 0, stream>>>(mems + (size_t)l * NB * NM * D, xb, memb);
      gemm(xb,    sa_Wq + wo, qb, NB * NQ,  D, D);
      gemm(memb,  sa_Wk + wo, kb, NB * KLEN, D, D);
      gemm(memb,  sa_Wv + wo, vb, NB * KLEN, D, D);
      gemm(r_emb, sa_Wr + wo, rb, KLEN, D, D);
      for (int b = 0; b < NB; ++b) {
        const float* qB = qb + (size_t)b * NQ * D;
        dim3 gs(KLEN / 128, NQ / 128, NH);
        k_qkt<false><<<gs, 256, 0, stream>>>(qB, kb + (size_t)b * KLEN * D, u_b, scb, KLEN);
        k_qkt<true><<<gs, 256, 0, stream>>>(qB, rb, v_b, scb, KLEN);
        k_softmax<KLEN, true><<<dim3(NQ, NH), 256, 0, stream>>>(scb);
        k_pv<KLEN><<<dim3(NQ / 128, NH), 256, 0, stream>>>(scb, vb + (size_t)b * KLEN * D,
                                                           avb + (size_t)b * NQ * D);
      }
      gemm(avb, sa_fcW + wo, yb, NB * NQ, D, D);
      k_ln<<<NB * NQ, 256, 0, stream>>>(xb, yb, sa_fcB + (size_t)l * D,
                                        ln1_g + (size_t)l * D, ln1_b + (size_t)l * D);
      gemm(xb,  ca_Wq + wo, qb, NB * NQ, D, D);
      gemm(enc, ca_Wk + wo, kb, NB * NE, D, D);
      gemm(enc, ca_Wv + wo, vb, NB * NE, D, D);
      for (int b = 0; b < NB; ++b) {
        const float* qB = qb + (size_t)b * NQ * D;
        dim3 gs(NE / 128, NQ / 128, NH);
        k_qkt<false><<<gs, 256, 0, stream>>>(qB, kb + (size_t)b * NE * D, nullptr, scb, NE);
        k_softmax<NE, false><<<dim3(NQ, NH), 256, 0, stream>>>(scb);
        k_pv<NE><<<dim3(NQ / 128, NH), 256, 0, stream>>>(scb, vb + (size_t)b * NE * D,
                                                         avb + (size_t)b * NQ * D);
      }
      gemm(avb, ca_fcW + wo, yb, NB * NQ, D, D);
      k_ln<<<NB * NQ, 256, 0, stream>>>(xb, yb, ca_fcB + (size_t)l * D,
                                        ln2_g + (size_t)l * D, ln2_b + (size_t)l * D);
      gemm(xb, ff_W1 + (size_t)l * D * DFF, hff, NB * NQ, DFF, D);
      k_bias_gelu<<<(NB * NQ * DFF) / 1024, 256, 0, stream>>>(hff, ff_b1 + (size_t)l * DFF);
      gemm(hff, ff_W2 + (size_t)l * DFF * D, yb, NB * NQ, D, DFF);
      k_ln<<<NB * NQ, 256, 0, stream>>>(xb, yb, ff_b2 + (size_t)l * D,
                                        ln3_g + (size_t)l * D, ln3_b + (size_t)l * D);
    }
    gemm(xb, out_W, out, NB * NQ, NV, D);
    return;
  }

  // ---------------- bf16x3 MFMA path ----------------
  auto asplit = [&](const float* A, int nelem) {         // activation -> ah/al
    k_split4<<<nelem / 1024, 256, 0, stream>>>(A, ah, al, nelem / 4);
  };
  auto wsplit = [&](const float* W, int K, int N) {      // weight [K][N] -> bh/bl [N][K]
    k_split_t<<<dim3(N / 32, K / 32), 256, 0, stream>>>(W, bh, bl, K, N);
  };
  auto mgemm = [&](float* Cp, int Md, int Nd, int Kd,
                   const unsigned short* pah, const unsigned short* pal) {
    if (Nd >= 2048) {
      k_mgemm<128><<<dim3(Nd / 128, Md / 128), 256, 0, stream>>>(pah, pal, bh, bl, Cp, Md, Nd, Kd);
    } else {
      k_mgemm<64><<<dim3(Nd / 64, Md / 128), 256, 0, stream>>>(pah, pal, bh, bl, Cp, Md, Nd, Kd);
    }
  };

  k_embed<<<NB * NQ, 256, 0, stream>>>(emb, ids, xb);
  k_posemb<<<KLEN, 256, 0, stream>>>(r_emb);
  // constants split once: relative-pos table and encoder outputs
  k_split4<<<(KLEN * D) / 1024, 256, 0, stream>>>(r_emb, rh, rl, (KLEN * D) / 4);
  k_split4<<<(NB * NE * D) / 1024, 256, 0, stream>>>(enc, ench, encl, (NB * NE * D) / 4);

  for (int l = 0; l < NL; ++l) {
    size_t wo = (size_t)l * D * D;
    // ---- self attention (TransformerXL relative) ----
    k_concat<<<NB * KLEN, 256, 0, stream>>>(mems + (size_t)l * NB * NM * D, xb, memb);
    asplit(xb, NB * NQ * D);
    wsplit(sa_Wq + wo, D, D);
    mgemm(qb, NB * NQ, D, D, ah, al);
    asplit(memb, NB * KLEN * D);
    wsplit(sa_Wk + wo, D, D);
    mgemm(kb, NB * KLEN, D, D, ah, al);
    wsplit(sa_Wv + wo, D, D);
    mgemm(vb, NB * KLEN, D, D, ah, al);
    wsplit(sa_Wr + wo, D, D);
    mgemm(rb, KLEN, D, D, rh, rl);
    for (int b = 0; b < NB; ++b) {
      const float* qB = qb + (size_t)b * NQ * D;
      dim3 gs(KLEN / 128, NQ / 128, NH);
      k_qkt<false><<<gs, 256, 0, stream>>>(qB, kb + (size_t)b * KLEN * D, u_b, scb, KLEN);
      k_qkt<true><<<gs, 256, 0, stream>>>(qB, rb, v_b, scb, KLEN);
      k_softmax<KLEN, true><<<dim3(NQ, NH), 256, 0, stream>>>(scb);
      k_pv<KLEN><<<dim3(NQ / 128, NH), 256, 0, stream>>>(scb, vb + (size_t)b * KLEN * D,
                                                         avb + (size_t)b * NQ * D);
    }
    asplit(avb, NB * NQ * D);
    wsplit(sa_fcW + wo, D, D);
    mgemm(yb, NB * NQ, D, D, ah, al);
    k_ln<<<NB * NQ, 256, 0, stream>>>(xb, yb, sa_fcB + (size_t)l * D,
                                      ln1_g + (size_t)l * D, ln1_b + (size_t)l * D);
    // ---- cross attention ----
    asplit(xb, NB * NQ * D);
    wsplit(ca_Wq + wo, D, D);
    mgemm(qb, NB * NQ, D, D, ah, al);
    wsplit(ca_Wk + wo, D, D);
    mgemm(kb, NB * NE, D, D, ench, encl);
    wsplit(ca_Wv + wo, D, D);
    mgemm(vb, NB * NE, D, D, ench, encl);
    for (int b = 0; b < NB; ++b) {
      const float* qB = qb + (size_t)b * NQ * D;
      dim3 gs(NE / 128, NQ / 128, NH);
      k_qkt<false><<<gs, 256, 0, stream>>>(qB, kb + (size_t)b * NE * D, nullptr, scb, NE);
      k_softmax<NE, false><<<dim3(NQ, NH), 256, 0, stream>>>(scb);
      k_pv<NE><<<dim3(NQ / 128, NH), 256, 0, stream>>>(scb, vb + (size_t)b * NE * D,
                                                       avb + (size_t)b * NQ * D);
    }
    asplit(avb, NB * NQ * D);
    wsplit(ca_fcW + wo, D, D);
    mgemm(yb, NB * NQ, D, D, ah, al);
    k_ln<<<NB * NQ, 256, 0, stream>>>(xb, yb, ca_fcB + (size_t)l * D,
                                      ln2_g + (size_t)l * D, ln2_b + (size_t)l * D);
    // ---- feed forward ----
    asplit(xb, NB * NQ * D);
    wsplit(ff_W1 + (size_t)l * D * DFF, D, DFF);
    mgemm(hff, NB * NQ, DFF, D, ah, al);
    k_bias_gelu<<<(NB * NQ * DFF) / 1024, 256, 0, stream>>>(hff, ff_b1 + (size_t)l * DFF);
    asplit(hff, NB * NQ * DFF);
    wsplit(ff_W2 + (size_t)l * DFF * D, DFF, D);
    mgemm(yb, NB * NQ, D, DFF, ah, al);
    k_ln<<<NB * NQ, 256, 0, stream>>>(xb, yb, ff_b2 + (size_t)l * D,
                                      ln3_g + (size_t)l * D, ln3_b + (size_t)l * D);
  }
  // ---- output projection ----
  asplit(xb, NB * NQ * D);
  wsplit(out_W, D, NV);
  mgemm(out, NB * NQ, NV, D, ah, al);
}

// Round 2
// 5125.837 us; speedup vs baseline: 2.4892x; 1.4480x over previous
//
#include <hip/hip_runtime.h>
#include <math.h>

// Problem dims (fixed by reference)
constexpr int NL = 4, D = 1024, NH = 16, DH = 64, DFF = 4096, NV = 8192;
constexpr int NB = 4, NQ = 512, NM = 512, NE = 512, KLEN = 1024; // KLEN = NM+NQ

using frag16 = __attribute__((ext_vector_type(8))) short;  // 8 bf16 = 4 VGPR
using f32x4  = __attribute__((ext_vector_type(4))) float;  // MFMA acc

// ---------------------------------------------------------------------------
// Embedding lookup: x[b,q,:] = emb[id] * sqrt(D) (=32)
__global__ __launch_bounds__(256) void k_embed(const float* __restrict__ emb,
                                               const int* __restrict__ ids,
                                               float* __restrict__ x) {
  int row = blockIdx.x;                 // 0..NB*NQ-1
  int id = ids[row];
  const float4* src = (const float4*)(emb + (size_t)id * D);
  float4* dst = (float4*)(x + (size_t)row * D);
  for (int i = threadIdx.x; i < D / 4; i += 256) {
    float4 t = src[i];
    t.x *= 32.f; t.y *= 32.f; t.z *= 32.f; t.w *= 32.f;
    dst[i] = t;
  }
}

// ---------------------------------------------------------------------------
// Relative positional embedding r_emb[p, d]
__global__ __launch_bounds__(256) void k_posemb(float* __restrict__ r_emb) {
  int p = blockIdx.x;
  float pos = (float)(KLEN - 1 - p);
  for (int d = threadIdx.x; d < D; d += 256) {
    int i = (d < D / 2) ? d : d - D / 2;
    float freq = (float)pow(10000.0, -(double)(2 * i) / (double)D);
    float a = pos * freq;
    r_emb[(size_t)p * D + d] = (d < D / 2) ? sinf(a) : cosf(a);
  }
}

// ---------------------------------------------------------------------------
// mem = concat(mems[l], x) along sequence
__global__ __launch_bounds__(256) void k_concat(const float* __restrict__ mems_l,
                                                const float* __restrict__ x,
                                                float* __restrict__ mem) {
  int row = blockIdx.x;                 // b*KLEN + t
  int b = row / KLEN, t = row % KLEN;
  const float4* src = (const float4*)((t < NM)
      ? (mems_l + ((size_t)b * NM + t) * D)
      : (x + ((size_t)b * NQ + (t - NM)) * D));
  float4* dst = (float4*)(mem + (size_t)row * D);
  for (int i = threadIdx.x; i < D / 4; i += 256) dst[i] = src[i];
}

// ---------------------------------------------------------------------------
// bf16 hi/lo split helpers (RNE). x == hi + lo to ~2^-17 rel.
__device__ inline void split2(float x, unsigned short& h, unsigned short& lo) {
  unsigned u = __float_as_uint(x);
  unsigned hr = (u + 0x7FFFu + ((u >> 16) & 1u)) & 0xFFFF0000u;
  h = (unsigned short)(hr >> 16);
  float r = x - __uint_as_float(hr);
  unsigned ur = __float_as_uint(r);
  lo = (unsigned short)((ur + 0x7FFFu + ((ur >> 16) & 1u)) >> 16);
}

// Elementwise split: A[n] fp32 -> H[n], L[n] bf16 (same layout, K-contiguous)
__global__ __launch_bounds__(256) void k_split4(const float* __restrict__ A,
                                                unsigned short* __restrict__ H,
                                                unsigned short* __restrict__ L,
                                                int n4) {
  int i = blockIdx.x * 256 + threadIdx.x;
  if (i >= n4) return;
  float4 f = ((const float4*)A)[i];
  ushort4 h, lo;
  split2(f.x, h.x, lo.x);
  split2(f.y, h.y, lo.y);
  split2(f.z, h.z, lo.z);
  split2(f.w, h.w, lo.w);
  ((ushort4*)H)[i] = h;
  ((ushort4*)L)[i] = lo;
}

// Transpose-split: W[K][N] fp32 -> H,L [N][K] bf16.
__global__ __launch_bounds__(256) void k_split_t(const float* __restrict__ W,
                                                 unsigned short* __restrict__ H,
                                                 unsigned short* __restrict__ L,
                                                 int K, int N) {
  __shared__ float t[32][33];
  int n0 = blockIdx.x * 32, k0 = blockIdx.y * 32;
  int tx = threadIdx.x & 31, ty = threadIdx.x >> 5;  // ty 0..7
#pragma unroll
  for (int i = 0; i < 4; ++i)
    t[ty + 8 * i][tx] = W[(size_t)(k0 + ty + 8 * i) * N + n0 + tx];
  __syncthreads();
#pragma unroll
  for (int i = 0; i < 4; ++i) {
    int n = n0 + ty + 8 * i, k = k0 + tx;
    unsigned short h, lo;
    split2(t[tx][ty + 8 * i], h, lo);
    H[(size_t)n * K + k] = h;
    L[(size_t)n * K + k] = lo;
  }
}

// ---------------------------------------------------------------------------
// bf16x3 MFMA GEMM: C[M][N] = (Ah+Al)[M][K] @ (Bh+Bl)[N][K]^T  (fp32 out)
template <int BN>
__global__ __launch_bounds__(256, 2) void k_mgemm(
    const unsigned short* __restrict__ Ah, const unsigned short* __restrict__ Al,
    const unsigned short* __restrict__ Bh, const unsigned short* __restrict__ Bl,
    float* __restrict__ C, int Mdim, int Ndim, int Kdim) {
  constexpr int NI = BN / 32;        // B-frags per wave (4 or 2)
  constexpr int WCN = BN / 2;        // wave N extent
  constexpr int NCB = BN / 16;       // 16-row chunks per B plane
  constexpr int NC = 16 + 2 * NCB;   // total staging chunks per K-tile
  constexpr int PA = 128 * 32;       // plane size (ushorts)
  constexpr int PB = BN * 32;
  constexpr int BUF = 2 * PA + 2 * PB;
  __shared__ __align__(16) unsigned short lds[2][BUF];

  const int tid = threadIdx.x;
  const int l = tid & 63, w = tid >> 6;
  const int wr = w >> 1, wc = w & 1;
  const int lr = l & 15, lg = l >> 4;
  const int m0 = blockIdx.y * 128, n0 = blockIdx.x * BN;
  const int sr = l >> 2, sg = l & 3;
  const int sgs = (sg ^ ((sr >> 1) & 3)) * 8;   // swizzled source granule
  const int glo = (lg ^ ((lr >> 1) & 3)) * 8;   // fragment-read swizzle

  f32x4 acc[4][NI];
#pragma unroll
  for (int i = 0; i < 4; ++i)
#pragma unroll
    for (int j = 0; j < NI; ++j)
      acc[i][j] = (f32x4){0.f, 0.f, 0.f, 0.f};

  auto stage = [&](int bb, int kt) {
    for (int cid = w; cid < NC; cid += 4) {
      const unsigned short* gb;
      int ldso;
      if (cid < 8) {
        gb = Ah + (size_t)(m0 + cid * 16 + sr) * Kdim;
        ldso = cid * 16 * 32;
      } else if (cid < 16) {
        gb = Al + (size_t)(m0 + (cid - 8) * 16 + sr) * Kdim;
        ldso = PA + (cid - 8) * 16 * 32;
      } else if (cid < 16 + NCB) {
        gb = Bh + (size_t)(n0 + (cid - 16) * 16 + sr) * Kdim;
        ldso = 2 * PA + (cid - 16) * 16 * 32;
      } else {
        gb = Bl + (size_t)(n0 + (cid - 16 - NCB) * 16 + sr) * Kdim;
        ldso = 2 * PA + PB + (cid - 16 - NCB) * 16 * 32;
      }
      const unsigned short* src = gb + kt + sgs;
      __builtin_amdgcn_global_load_lds(
          (const __attribute__((address_space(1))) void*)src,
          (__attribute__((address_space(3))) void*)&lds[bb][ldso], 16, 0, 0);
    }
  };

  auto comp = [&](int bb) {
    frag16 af[4], alf[4], bf[NI], blf[NI];
#pragma unroll
    for (int mi = 0; mi < 4; ++mi) {
      int ro = (wr * 64 + mi * 16 + lr) * 32 + glo;
      af[mi]  = *(const frag16*)&lds[bb][ro];
      alf[mi] = *(const frag16*)&lds[bb][PA + ro];
    }
#pragma unroll
    for (int ni = 0; ni < NI; ++ni) {
      int ro = (wc * WCN + ni * 16 + lr) * 32 + glo;
      bf[ni]  = *(const frag16*)&lds[bb][2 * PA + ro];
      blf[ni] = *(const frag16*)&lds[bb][2 * PA + PB + ro];
    }
#pragma unroll
    for (int mi = 0; mi < 4; ++mi)
#pragma unroll
      for (int ni = 0; ni < NI; ++ni) {
        acc[mi][ni] = __builtin_amdgcn_mfma_f32_16x16x32_bf16(af[mi], bf[ni], acc[mi][ni], 0, 0, 0);
        acc[mi][ni] = __builtin_amdgcn_mfma_f32_16x16x32_bf16(af[mi], blf[ni], acc[mi][ni], 0, 0, 0);
        acc[mi][ni] = __builtin_amdgcn_mfma_f32_16x16x32_bf16(alf[mi], bf[ni], acc[mi][ni], 0, 0, 0);
      }
  };

  const int NT = Kdim / 32;
  stage(0, 0);
  __syncthreads();
  int bb = 0;
  for (int t = 0; t < NT; ++t) {
    if (t + 1 < NT) stage(bb ^ 1, (t + 1) * 32);
    comp(bb);
    __syncthreads();
    bb ^= 1;
  }
#pragma unroll
  for (int mi = 0; mi < 4; ++mi)
#pragma unroll
    for (int ni = 0; ni < NI; ++ni) {
      int row = m0 + wr * 64 + mi * 16 + lg * 4;
      int col = n0 + wc * WCN + ni * 16 + lr;
#pragma unroll
      for (int j = 0; j < 4; ++j)
        C[(size_t)(row + j) * Ndim + col] = acc[mi][ni][j];
    }
}

// ---------------------------------------------------------------------------
// MFMA attention scores: C[h][i][j] (+)= (qh+ql)[i,hslice]·(Bh+Bl)[j,hslice]
// K = DH = 64, single-shot LDS (no K loop). SHIFT: BD scatter-add (rel_shift).
template <bool SHIFT>
__global__ __launch_bounds__(256, 2) void k_mqkt(
    const unsigned short* __restrict__ Ah, const unsigned short* __restrict__ Al,
    const unsigned short* __restrict__ Bh, const unsigned short* __restrict__ Bl,
    float* __restrict__ C, int cols) {
  constexpr int PT = 2 * 128 * 32;     // plane tile (both 32-k subtiles), u16
  __shared__ __align__(16) unsigned short lds[4 * PT];   // 64 KB
  const int tid = threadIdx.x;
  const int l = tid & 63, w = tid >> 6;
  const int wr = w >> 1, wc = w & 1;
  const int lr = l & 15, lg = l >> 4;
  const int h = blockIdx.z;
  const int m0 = blockIdx.y * 128, n0 = blockIdx.x * 128;
  const int sr = l >> 2;
  const int sgs = ((l & 3) ^ ((sr >> 1) & 3)) * 8;
  const int glo = (lg ^ ((lr >> 1) & 3)) * 8;
  const unsigned short* pb[4] = {Ah + h * DH, Al + h * DH, Bh + h * DH, Bl + h * DH};
  for (int cid = w; cid < 64; cid += 4) {
    int p = cid >> 4, c = cid & 15, kt = c >> 3, rb2 = c & 7;
    int row0 = (p < 2 ? m0 : n0) + rb2 * 16 + sr;
    const unsigned short* src = pb[p] + (size_t)row0 * D + kt * 32 + sgs;
    int dst = p * PT + ((kt * 8 + rb2) * 16 + sr) * 32 + (l & 3) * 8;
    __builtin_amdgcn_global_load_lds(
        (const __attribute__((address_space(1))) void*)src,
        (__attribute__((address_space(3))) void*)&lds[dst], 16, 0, 0);
  }
  f32x4 acc[4][4];
#pragma unroll
  for (int i = 0; i < 4; ++i)
#pragma unroll
    for (int j = 0; j < 4; ++j) acc[i][j] = (f32x4){0.f, 0.f, 0.f, 0.f};
  __syncthreads();
#pragma unroll
  for (int kt = 0; kt < 2; ++kt) {
    frag16 af[4], alf[4], bf[4], blf[4];
#pragma unroll
    for (int mi = 0; mi < 4; ++mi) {
      int ro = (kt * 128 + wr * 64 + mi * 16 + lr) * 32 + glo;
      af[mi]  = *(const frag16*)&lds[0 * PT + ro];
      alf[mi] = *(const frag16*)&lds[1 * PT + ro];
    }
#pragma unroll
    for (int ni = 0; ni < 4; ++ni) {
      int ro = (kt * 128 + wc * 64 + ni * 16 + lr) * 32 + glo;
      bf[ni]  = *(const frag16*)&lds[2 * PT + ro];
      blf[ni] = *(const frag16*)&lds[3 * PT + ro];
    }
#pragma unroll
    for (int mi = 0; mi < 4; ++mi)
#pragma unroll
      for (int ni = 0; ni < 4; ++ni) {
        acc[mi][ni] = __builtin_amdgcn_mfma_f32_16x16x32_bf16(af[mi], bf[ni], acc[mi][ni], 0, 0, 0);
        acc[mi][ni] = __builtin_amdgcn_mfma_f32_16x16x32_bf16(af[mi], blf[ni], acc[mi][ni], 0, 0, 0);
        acc[mi][ni] = __builtin_amdgcn_mfma_f32_16x16x32_bf16(alf[mi], bf[ni], acc[mi][ni], 0, 0, 0);
      }
  }
  float* Cb = C + (size_t)h * NQ * cols;
  if (!SHIFT) {
#pragma unroll
    for (int mi = 0; mi < 4; ++mi)
#pragma unroll
      for (int ni = 0; ni < 4; ++ni) {
        int row = m0 + wr * 64 + mi * 16 + lg * 4;
        int col = n0 + wc * 64 + ni * 16 + lr;
#pragma unroll
        for (int j = 0; j < 4; ++j)
          Cb[(size_t)(row + j) * cols + col] = acc[mi][ni][j];
      }
  } else {
#pragma unroll
    for (int mi = 0; mi < 4; ++mi)
#pragma unroll
      for (int ni = 0; ni < 4; ++ni) {
        int col = n0 + wc * 64 + ni * 16 + lr;
#pragma unroll
        for (int j = 0; j < 4; ++j) {
          int ig = m0 + wr * 64 + mi * 16 + lg * 4 + j;
          int jj = col - (NQ - 1) + ig;
          if (jj >= 0) Cb[(size_t)ig * cols + jj] += acc[mi][ni][j];
        }
      }
  }
}

// ---------------------------------------------------------------------------
// uk[b][h][j] = sum_d bias[h][d] * rows[(b*KLEN+j)][h*DH+d]  (fp32 exact)
__global__ __launch_bounds__(256) void k_dotbias(const float* __restrict__ bias,
                                                 const float* __restrict__ rows,
                                                 float* __restrict__ out, int nrows) {
  int jr = blockIdx.x * 256 + threadIdx.x;
  int h = blockIdx.y;
  if (jr >= nrows) return;
  const float4* rp = (const float4*)(rows + (size_t)jr * D + h * DH);
  const float4* bp = (const float4*)(bias + h * DH);
  float s = 0.f;
#pragma unroll
  for (int q = 0; q < DH / 4; ++q) {
    float4 a = rp[q], c = bp[q];
    s += a.x * c.x + a.y * c.y + a.z * c.z + a.w * c.w;
  }
  int b_ = jr >> 10, jj = jr & 1023;  // KLEN = 1024
  out[((size_t)(b_ * NH + h)) * KLEN + jj] = s;
}

// ---------------------------------------------------------------------------
// Softmax (bias-corrected) -> bf16 hi/lo P planes.
// MASK (SA): s = (sc + uk[h][j] + vr[h][j+NQ-1-i]) * 0.125, mask j > NM+i.
// !MASK (CA): s = sc * 0.125.
template <int KL, bool MASK>
__global__ __launch_bounds__(256) void k_softmax2(const float* __restrict__ sc,
                                                  const float* __restrict__ uk,
                                                  const float* __restrict__ vr,
                                                  unsigned short* __restrict__ Ph,
                                                  unsigned short* __restrict__ Pl) {
  int i = blockIdx.x, h = blockIdx.y, tid = threadIdx.x;
  const float* r = sc + ((size_t)h * NQ + i) * KL;
  __shared__ float red[256];
  constexpr int NV4 = KL / 4;
  float4 v = {-1e30f, -1e30f, -1e30f, -1e30f};
  if (tid < NV4) {
    v = ((const float4*)r)[tid];
    int j = tid * 4;
    if (MASK) {
      float4 ukv = *(const float4*)(uk + (size_t)h * KLEN + j);
      const float* vrh = vr + (size_t)h * KLEN;
      int base = j + (NQ - 1) - i;
      v.x += ukv.x + ((base + 0 < KLEN) ? vrh[base + 0] : 0.f);
      v.y += ukv.y + ((base + 1 < KLEN) ? vrh[base + 1] : 0.f);
      v.z += ukv.z + ((base + 2 < KLEN) ? vrh[base + 2] : 0.f);
      v.w += ukv.w + ((base + 3 < KLEN) ? vrh[base + 3] : 0.f);
      if (j + 0 > NM + i) v.x = -1e30f;
      if (j + 1 > NM + i) v.y = -1e30f;
      if (j + 2 > NM + i) v.z = -1e30f;
      if (j + 3 > NM + i) v.w = -1e30f;
    }
    v.x *= 0.125f; v.y *= 0.125f; v.z *= 0.125f; v.w *= 0.125f;
  }
  red[tid] = fmaxf(fmaxf(v.x, v.y), fmaxf(v.z, v.w));
  __syncthreads();
  for (int off = 128; off > 0; off >>= 1) {
    if (tid < off) red[tid] = fmaxf(red[tid], red[tid + off]);
    __syncthreads();
  }
  float gm = red[0];
  __syncthreads();
  float4 e = {0.f, 0.f, 0.f, 0.f};
  if (tid < NV4) {
    e.x = __expf(v.x - gm);
    e.y = __expf(v.y - gm);
    e.z = __expf(v.z - gm);
    e.w = __expf(v.w - gm);
  }
  red[tid] = e.x + e.y + e.z + e.w;
  __syncthreads();
  for (int off = 128; off > 0; off >>= 1) {
    if (tid < off) red[tid] += red[tid + off];
    __syncthreads();
  }
  float inv = 1.f / red[0];
  if (tid < NV4) {
    e.x *= inv; e.y *= inv; e.z *= inv; e.w *= inv;
    ushort4 hh, ll;
    split2(e.x, hh.x, ll.x);
    split2(e.y, hh.y, ll.y);
    split2(e.z, hh.z, ll.z);
    split2(e.w, hh.w, ll.w);
    size_t o = ((size_t)h * NQ + i) * (KL / 4) + tid;
    ((ushort4*)Ph)[o] = hh;
    ((ushort4*)Pl)[o] = ll;
  }
}

// ---------------------------------------------------------------------------
// MFMA PV: av[i][h*DH+d] = sum_j (Ph+Pl)[h][i][j] * (Vh+Vl)[h*DH+d][j]
// BM=64 (grid x = NQ/64), BN=64 (=DH), BK=32, double-buffered.
template <int KL>
__global__ __launch_bounds__(256, 4) void k_mpv(
    const unsigned short* __restrict__ Ph, const unsigned short* __restrict__ Pl,
    const unsigned short* __restrict__ Vh, const unsigned short* __restrict__ Vl,
    float* __restrict__ av) {
  constexpr int PP = 64 * 32;  // plane per K-tile (u16)
  __shared__ __align__(16) unsigned short lds[2][4 * PP];   // 32 KB
  const int tid = threadIdx.x;
  const int l = tid & 63, w = tid >> 6;
  const int wr = w >> 1, wc = w & 1;
  const int lr = l & 15, lg = l >> 4;
  const int h = blockIdx.y;
  const int m0 = blockIdx.x * 64;
  const int sr = l >> 2;
  const int sgs = ((l & 3) ^ ((sr >> 1) & 3)) * 8;
  const int glo = (lg ^ ((lr >> 1) & 3)) * 8;
  const unsigned short* pb[4] = {
      Ph + ((size_t)h * NQ + m0) * KL, Pl + ((size_t)h * NQ + m0) * KL,
      Vh + (size_t)h * DH * KL,        Vl + (size_t)h * DH * KL};
  f32x4 acc[2][2];
#pragma unroll
  for (int i = 0; i < 2; ++i)
#pragma unroll
    for (int j = 0; j < 2; ++j) acc[i][j] = (f32x4){0.f, 0.f, 0.f, 0.f};

  auto stage = [&](int bb, int k0) {
    for (int cid = w; cid < 16; cid += 4) {
      int p = cid >> 2, c = cid & 3;
      const unsigned short* src = pb[p] + (size_t)(c * 16 + sr) * KL + k0 + sgs;
      int dst = p * PP + (c * 16 + sr) * 32 + (l & 3) * 8;
      __builtin_amdgcn_global_load_lds(
          (const __attribute__((address_space(1))) void*)src,
          (__attribute__((address_space(3))) void*)&lds[bb][dst], 16, 0, 0);
    }
  };
  auto comp = [&](int bb) {
    frag16 pf[2], plf[2], vf[2], vlf[2];
#pragma unroll
    for (int mi = 0; mi < 2; ++mi) {
      int ro = (wr * 32 + mi * 16 + lr) * 32 + glo;
      pf[mi]  = *(const frag16*)&lds[bb][0 * PP + ro];
      plf[mi] = *(const frag16*)&lds[bb][1 * PP + ro];
    }
#pragma unroll
    for (int ni = 0; ni < 2; ++ni) {
      int ro = (wc * 32 + ni * 16 + lr) * 32 + glo;
      vf[ni]  = *(const frag16*)&lds[bb][2 * PP + ro];
      vlf[ni] = *(const frag16*)&lds[bb][3 * PP + ro];
    }
#pragma unroll
    for (int mi = 0; mi < 2; ++mi)
#pragma unroll
      for (int ni = 0; ni < 2; ++ni) {
        acc[mi][ni] = __builtin_amdgcn_mfma_f32_16x16x32_bf16(pf[mi], vf[ni], acc[mi][ni], 0, 0, 0);
        acc[mi][ni] = __builtin_amdgcn_mfma_f32_16x16x32_bf16(pf[mi], vlf[ni], acc[mi][ni], 0, 0, 0);
        acc[mi][ni] = __builtin_amdgcn_mfma_f32_16x16x32_bf16(plf[mi], vf[ni], acc[mi][ni], 0, 0, 0);
      }
  };

  constexpr int NT = KL / 32;
  stage(0, 0);
  __syncthreads();
  int bb = 0;
  for (int t = 0; t < NT; ++t) {
    if (t + 1 < NT) stage(bb ^ 1, (t + 1) * 32);
    comp(bb);
    __syncthreads();
    bb ^= 1;
  }
#pragma unroll
  for (int mi = 0; mi < 2; ++mi)
#pragma unroll
    for (int ni = 0; ni < 2; ++ni) {
      int row = m0 + wr * 32 + mi * 16 + lg * 4;
      int col = wc * 32 + ni * 16 + lr;
#pragma unroll
      for (int j = 0; j < 4; ++j)
        av[(size_t)(row + j) * D + h * DH + col] = acc[mi][ni][j];
    }
}

// ---------------------------------------------------------------------------
// fp32 SGEMM (fallback tier only)
__global__ __launch_bounds__(256) void k_gemm(const float* __restrict__ A,
                                              const float* __restrict__ Bm,
                                              float* __restrict__ C,
                                              int Md, int Nd, int Kd) {
  __shared__ float As[16][132];   // [k][m]
  __shared__ float Bs[16][128];   // [k][n]
  int tid = threadIdx.x;
  int tx = tid & 15, ty = tid >> 4;
  int m0 = blockIdx.y * 128, n0 = blockIdx.x * 128;
  float acc[8][8] = {{0.f}};
  for (int k0 = 0; k0 < Kd; k0 += 16) {
#pragma unroll
    for (int ld = 0; ld < 2; ++ld) {
      int idx = tid + ld * 256;
      int row = idx >> 2, kq = idx & 3;
      float4 t = *(const float4*)(A + (size_t)(m0 + row) * Kd + k0 + kq * 4);
      As[kq * 4 + 0][row] = t.x;
      As[kq * 4 + 1][row] = t.y;
      As[kq * 4 + 2][row] = t.z;
      As[kq * 4 + 3][row] = t.w;
      int kk2 = idx >> 5, nq = idx & 31;
      *(float4*)&Bs[kk2][nq * 4] = *(const float4*)(Bm + (size_t)(k0 + kk2) * Nd + n0 + nq * 4);
    }
    __syncthreads();
#pragma unroll
    for (int kkk = 0; kkk < 16; ++kkk) {
      float a[8], bq[8];
      *(float4*)&a[0] = *(const float4*)&As[kkk][ty * 8];
      *(float4*)&a[4] = *(const float4*)&As[kkk][ty * 8 + 4];
      *(float4*)&bq[0] = *(const float4*)&Bs[kkk][tx * 8];
      *(float4*)&bq[4] = *(const float4*)&Bs[kkk][tx * 8 + 4];
#pragma unroll
      for (int i = 0; i < 8; ++i)
#pragma unroll
        for (int j = 0; j < 8; ++j)
          acc[i][j] = fmaf(a[i], bq[j], acc[i][j]);
    }
    __syncthreads();
  }
#pragma unroll
  for (int i = 0; i < 8; ++i) {
    float* cr = C + (size_t)(m0 + ty * 8 + i) * Nd + n0 + tx * 8;
    float4 o1 = {acc[i][0], acc[i][1], acc[i][2], acc[i][3]};
    float4 o2 = {acc[i][4], acc[i][5], acc[i][6], acc[i][7]};
    *(float4*)cr = o1;
    *(float4*)(cr + 4) = o2;
  }
}

// ---------------------------------------------------------------------------
// fp32 score NT-GEMM (mid-tier fallback)
template <bool SHIFT>
__global__ __launch_bounds__(256) void k_qkt(const float* __restrict__ A,
                                             const float* __restrict__ Bm,
                                             const float* __restrict__ bias,
                                             float* __restrict__ C,
                                             int cols) {
  __shared__ float As[16][132];
  __shared__ float Bs[16][132];
  int h = blockIdx.z;
  int m0 = blockIdx.y * 128, n0 = blockIdx.x * 128;
  const float* Ab = A + h * DH;
  const float* Bb = Bm + h * DH;
  float* Cb = C + (size_t)h * NQ * cols;
  int tid = threadIdx.x, tx = tid & 15, ty = tid >> 4;
  float acc[8][8] = {{0.f}};
  for (int k0 = 0; k0 < DH; k0 += 16) {
#pragma unroll
    for (int ld = 0; ld < 2; ++ld) {
      int idx = tid + ld * 256;
      int row = idx >> 2, kq = idx & 3;
      float4 t = *(const float4*)(Ab + (size_t)(m0 + row) * D + k0 + kq * 4);
      float4 bv = {0.f, 0.f, 0.f, 0.f};
      if (bias) bv = *(const float4*)(bias + h * DH + k0 + kq * 4);
      As[kq * 4 + 0][row] = t.x + bv.x;
      As[kq * 4 + 1][row] = t.y + bv.y;
      As[kq * 4 + 2][row] = t.z + bv.z;
      As[kq * 4 + 3][row] = t.w + bv.w;
      float4 tb = *(const float4*)(Bb + (size_t)(n0 + row) * D + k0 + kq * 4);
      Bs[kq * 4 + 0][row] = tb.x;
      Bs[kq * 4 + 1][row] = tb.y;
      Bs[kq * 4 + 2][row] = tb.z;
      Bs[kq * 4 + 3][row] = tb.w;
    }
    __syncthreads();
#pragma unroll
    for (int kkk = 0; kkk < 16; ++kkk) {
      float a[8], bq[8];
      *(float4*)&a[0] = *(const float4*)&As[kkk][ty * 8];
      *(float4*)&a[4] = *(const float4*)&As[kkk][ty * 8 + 4];
      *(float4*)&bq[0] = *(const float4*)&Bs[kkk][tx * 8];
      *(float4*)&bq[4] = *(const float4*)&Bs[kkk][tx * 8 + 4];
#pragma unroll
      for (int i = 0; i < 8; ++i)
#pragma unroll
        for (int j = 0; j < 8; ++j)
          acc[i][j] = fmaf(a[i], bq[j], acc[i][j]);
    }
    __syncthreads();
  }
  if (!SHIFT) {
#pragma unroll
    for (int i = 0; i < 8; ++i) {
      float* cr = Cb + (size_t)(m0 + ty * 8 + i) * cols + n0 + tx * 8;
      float4 o1 = {acc[i][0], acc[i][1], acc[i][2], acc[i][3]};
      float4 o2 = {acc[i][4], acc[i][5], acc[i][6], acc[i][7]};
      *(float4*)cr = o1;
      *(float4*)(cr + 4) = o2;
    }
  } else {
#pragma unroll
    for (int i = 0; i < 8; ++i) {
      int ig = m0 + ty * 8 + i;
      float* cr = Cb + (size_t)ig * cols;
#pragma unroll
      for (int j = 0; j < 8; ++j) {
        int p = n0 + tx * 8 + j;
        int jj = p - (NQ - 1) + ig;
        if (jj >= 0) cr[jj] += acc[i][j];
      }
    }
  }
}

// ---------------------------------------------------------------------------
// fp32 softmax (mid-tier fallback)
template <int KL, bool MASK>
__global__ __launch_bounds__(256) void k_softmax(float* __restrict__ sc) {
  int i = blockIdx.x, h = blockIdx.y, tid = threadIdx.x;
  float* r = sc + ((size_t)h * NQ + i) * KL;
  __shared__ float red[256];
  constexpr int NV4 = KL / 4;
  float4 v = {-1e30f, -1e30f, -1e30f, -1e30f};
  if (tid < NV4) {
    v = ((float4*)r)[tid];
    v.x *= 0.125f; v.y *= 0.125f; v.z *= 0.125f; v.w *= 0.125f;
    if (MASK) {
      int j = tid * 4;
      if (j + 0 > NM + i) v.x = -1e30f;
      if (j + 1 > NM + i) v.y = -1e30f;
      if (j + 2 > NM + i) v.z = -1e30f;
      if (j + 3 > NM + i) v.w = -1e30f;
    }
  }
  red[tid] = fmaxf(fmaxf(v.x, v.y), fmaxf(v.z, v.w));
  __syncthreads();
  for (int off = 128; off > 0; off >>= 1) {
    if (tid < off) red[tid] = fmaxf(red[tid], red[tid + off]);
    __syncthreads();
  }
  float gm = red[0];
  __syncthreads();
  float4 e = {0.f, 0.f, 0.f, 0.f};
  if (tid < NV4) {
    e.x = __expf(v.x - gm);
    e.y = __expf(v.y - gm);
    e.z = __expf(v.z - gm);
    e.w = __expf(v.w - gm);
  }
  red[tid] = e.x + e.y + e.z + e.w;
  __syncthreads();
  for (int off = 128; off > 0; off >>= 1) {
    if (tid < off) red[tid] += red[tid + off];
    __syncthreads();
  }
  float inv = 1.f / red[0];
  if (tid < NV4) {
    e.x *= inv; e.y *= inv; e.z *= inv; e.w *= inv;
    ((float4*)r)[tid] = e;
  }
}

// ---------------------------------------------------------------------------
// fp32 PV (mid-tier fallback)
template <int KL>
__global__ __launch_bounds__(256) void k_pv(const float* __restrict__ sc,
                                            const float* __restrict__ V,
                                            float* __restrict__ av) {
  __shared__ float As[16][132];
  __shared__ float Bs[16][68];
  int h = blockIdx.y;
  int m0 = blockIdx.x * 128;
  const float* P = sc + (size_t)h * NQ * KL;
  const float* Vb = V + h * DH;
  int tid = threadIdx.x, tx = tid & 15, ty = tid >> 4;
  float acc[8][4] = {{0.f}};
  for (int k0 = 0; k0 < KL; k0 += 16) {
#pragma unroll
    for (int ld = 0; ld < 2; ++ld) {
      int idx = tid + ld * 256;
      int row = idx >> 2, kq = idx & 3;
      float4 t = *(const float4*)(P + (size_t)(m0 + row) * KL + k0 + kq * 4);
      As[kq * 4 + 0][row] = t.x;
      As[kq * 4 + 1][row] = t.y;
      As[kq * 4 + 2][row] = t.z;
      As[kq * 4 + 3][row] = t.w;
    }
    {
      int kk = tid >> 4, nq = tid & 15;
      *(float4*)&Bs[kk][nq * 4] = *(const float4*)(Vb + (size_t)(k0 + kk) * D + nq * 4);
    }
    __syncthreads();
#pragma unroll
    for (int kkk = 0; kkk < 16; ++kkk) {
      float a[8], bq[4];
      *(float4*)&a[0] = *(const float4*)&As[kkk][ty * 8];
      *(float4*)&a[4] = *(const float4*)&As[kkk][ty * 8 + 4];
      *(float4*)&bq[0] = *(const float4*)&Bs[kkk][tx * 4];
#pragma unroll
      for (int i = 0; i < 8; ++i)
#pragma unroll
        for (int j = 0; j < 4; ++j)
          acc[i][j] = fmaf(a[i], bq[j], acc[i][j]);
    }
    __syncthreads();
  }
#pragma unroll
  for (int i = 0; i < 8; ++i) {
    float4 o = {acc[i][0], acc[i][1], acc[i][2], acc[i][3]};
    *(float4*)(av + (size_t)(m0 + ty * 8 + i) * D + h * DH + tx * 4) = o;
  }
}

// ---------------------------------------------------------------------------
// x = LayerNorm(x + y + bias) * g + b
__global__ __launch_bounds__(256) void k_ln(float* __restrict__ x,
                                            const float* __restrict__ y,
                                            const float* __restrict__ bias,
                                            const float* __restrict__ g,
                                            const float* __restrict__ bb) {
  int row = blockIdx.x;
  int tid = threadIdx.x;
  __shared__ float red[256];
  size_t base = (size_t)row * D + tid * 4;
  float4 xv = *(const float4*)(x + base);
  float4 yv = *(const float4*)(y + base);
  float4 bv = *(const float4*)(bias + tid * 4);
  float v0 = xv.x + yv.x + bv.x;
  float v1 = xv.y + yv.y + bv.y;
  float v2 = xv.z + yv.z + bv.z;
  float v3 = xv.w + yv.w + bv.w;
  red[tid] = v0 + v1 + v2 + v3;
  __syncthreads();
  for (int off = 128; off > 0; off >>= 1) {
    if (tid < off) red[tid] += red[tid + off];
    __syncthreads();
  }
  float mu = red[0] * (1.f / D);
  __syncthreads();
  v0 -= mu; v1 -= mu; v2 -= mu; v3 -= mu;
  red[tid] = v0 * v0 + v1 * v1 + v2 * v2 + v3 * v3;
  __syncthreads();
  for (int off = 128; off > 0; off >>= 1) {
    if (tid < off) red[tid] += red[tid + off];
    __syncthreads();
  }
  float inv = rsqrtf(red[0] * (1.f / D) + 1e-5f);
  float4 gv = *(const float4*)(g + tid * 4);
  float4 bbv = *(const float4*)(bb + tid * 4);
  float4 o;
  o.x = v0 * inv * gv.x + bbv.x;
  o.y = v1 * inv * gv.y + bbv.y;
  o.z = v2 * inv * gv.z + bbv.z;
  o.w = v3 * inv * gv.w + bbv.w;
  *(float4*)(x + base) = o;
}

// ---------------------------------------------------------------------------
// h = gelu(h + b1), exact erf variant
__global__ __launch_bounds__(256) void k_bias_gelu(float* __restrict__ h,
                                                   const float* __restrict__ b1) {
  size_t idx = ((size_t)blockIdx.x * 256 + threadIdx.x) * 4;
  int col = (int)(idx % DFF);
  float4 t = *(float4*)(h + idx);
  float4 bv = *(const float4*)(b1 + col);
  float a0 = t.x + bv.x, a1 = t.y + bv.y, a2 = t.z + bv.z, a3 = t.w + bv.w;
  const float inv_sqrt2 = 0.70710678118654752f;
  t.x = 0.5f * a0 * (1.f + erff(a0 * inv_sqrt2));
  t.y = 0.5f * a1 * (1.f + erff(a1 * inv_sqrt2));
  t.z = 0.5f * a2 * (1.f + erff(a2 * inv_sqrt2));
  t.w = 0.5f * a3 * (1.f + erff(a3 * inv_sqrt2));
  *(float4*)(h + idx) = t;
}

// ---------------------------------------------------------------------------
extern "C" void kernel_launch(void* const* d_in, const int* in_sizes, int n_in,
                              void* d_out, int out_size, void* d_ws, size_t ws_size,
                              hipStream_t stream) {
  const float* enc    = (const float*)d_in[0];
  const float* mems   = (const float*)d_in[1];
  const float* emb    = (const float*)d_in[2];
  const float* u_b    = (const float*)d_in[3];
  const float* v_b    = (const float*)d_in[4];
  const float* sa_Wq  = (const float*)d_in[5];
  const float* sa_Wk  = (const float*)d_in[6];
  const float* sa_Wv  = (const float*)d_in[7];
  const float* sa_Wr  = (const float*)d_in[8];
  const float* sa_fcW = (const float*)d_in[9];
  const float* sa_fcB = (const float*)d_in[10];
  const float* ln1_g  = (const float*)d_in[11];
  const float* ln1_b  = (const float*)d_in[12];
  const float* ca_Wq  = (const float*)d_in[13];
  const float* ca_Wk  = (const float*)d_in[14];
  const float* ca_Wv  = (const float*)d_in[15];
  const float* ca_fcW = (const float*)d_in[16];
  const float* ca_fcB = (const float*)d_in[17];
  const float* ln2_g  = (const float*)d_in[18];
  const float* ln2_b  = (const float*)d_in[19];
  const float* ff_W1  = (const float*)d_in[20];
  const float* ff_b1  = (const float*)d_in[21];
  const float* ff_W2  = (const float*)d_in[22];
  const float* ff_b2  = (const float*)d_in[23];
  const float* ln3_g  = (const float*)d_in[24];
  const float* ln3_b  = (const float*)d_in[25];
  const float* out_W  = (const float*)d_in[26];
  const int*   ids    = (const int*)d_in[27];
  float* out = (float*)d_out;

  // --- Workspace layout ---
  float* ws    = (float*)d_ws;
  float* r_emb = ws;                                  // 1M
  float* xb    = r_emb + (size_t)KLEN * D;            // 2M
  float* yb    = xb   + (size_t)NB * NQ * D;          // 2M
  float* avb   = yb   + (size_t)NB * NQ * D;          // 2M
  float* qb    = avb  + (size_t)NB * NQ * D;          // 2M
  float* memb  = qb   + (size_t)NB * NQ * D;          // 4M
  float* kb    = memb + (size_t)NB * KLEN * D;        // 4M
  float* vb    = kb   + (size_t)NB * KLEN * D;        // 4M
  float* rb    = vb   + (size_t)NB * KLEN * D;        // 1M
  float* scb   = rb   + (size_t)KLEN * D;             // 8M
  float* hff   = memb;  // FF hidden aliases memb+kb
  unsigned short* ah   = (unsigned short*)(scb + (size_t)NH * NQ * KLEN); // 8M u16
  unsigned short* al   = ah + (size_t)8 * 1024 * 1024;                    // 8M
  unsigned short* bh   = al + (size_t)8 * 1024 * 1024;                    // 8M
  unsigned short* bl   = bh + (size_t)8 * 1024 * 1024;                    // 8M
  unsigned short* ench = bl + (size_t)8 * 1024 * 1024;                    // 2M
  unsigned short* encl = ench + (size_t)NB * NE * D;                      // 2M
  unsigned short* rh   = encl + (size_t)NB * NE * D;                      // 1M
  unsigned short* rl   = rh + (size_t)KLEN * D;                           // 1M
  // --- attention-MFMA extension region ---
  unsigned short* qh   = rl + (size_t)KLEN * D;                           // 2M
  unsigned short* ql   = qh + (size_t)NB * NQ * D;                        // 2M
  unsigned short* rbh  = ql + (size_t)NB * NQ * D;                        // 1M
  unsigned short* rbl  = rbh + (size_t)KLEN * D;                          // 1M
  float* ukb = (float*)(rbl + (size_t)KLEN * D);                          // 64K fl
  float* vrb = ukb + (size_t)NB * NH * KLEN;                              // 16K fl
  // aliases (dead regions during attention):
  unsigned short* kh  = ah;                           // k planes
  unsigned short* kl  = ah + (size_t)4 * 1024 * 1024;
  unsigned short* vth = al;                           // V^T planes
  unsigned short* vtl = al + (size_t)4 * 1024 * 1024;
  unsigned short* ph  = bh;                           // P planes
  unsigned short* pl  = bl;

  const size_t WS1 = 205520896ull;                    // mfma projections
  const size_t WS2 = WS1 + 12582912ull + 327680ull;   // + mfma attention
  const bool tier1 = ws_size >= WS1;
  const bool tier2 = ws_size >= WS2;

  if (!tier1) {
    // ---------- fp32 fallback ----------
    auto gemm = [&](const float* A, const float* Bp, float* C, int Md, int Nd, int Kd) {
      dim3 g(Nd / 128, Md / 128);
      k_gemm<<<g, 256, 0, stream>>>(A, Bp, C, Md, Nd, Kd);
    };
    k_embed<<<NB * NQ, 256, 0, stream>>>(emb, ids, xb);
    k_posemb<<<KLEN, 256, 0, stream>>>(r_emb);
    for (int l = 0; l < NL; ++l) {
      size_t wo = (size_t)l * D * D;
      k_concat<<<NB * KLEN, 256, 0, stream>>>(mems + (size_t)l * NB * NM * D, xb, memb);
      gemm(xb,    sa_Wq + wo, qb, NB * NQ,  D, D);
      gemm(memb,  sa_Wk + wo, kb, NB * KLEN, D, D);
      gemm(memb,  sa_Wv + wo, vb, NB * KLEN, D, D);
      gemm(r_emb, sa_Wr + wo, rb, KLEN, D, D);
      for (int b = 0; b < NB; ++b) {
        const float* qB = qb + (size_t)b * NQ * D;
        dim3 gs(KLEN / 128, NQ / 128, NH);
        k_qkt<false><<<gs, 256, 0, stream>>>(qB, kb + (size_t)b * KLEN * D, u_b, scb, KLEN);
        k_qkt<true><<<gs, 256, 0, stream>>>(qB, rb, v_b, scb, KLEN);
        k_softmax<KLEN, true><<<dim3(NQ, NH), 256, 0, stream>>>(scb);
        k_pv<KLEN><<<dim3(NQ / 128, NH), 256, 0, stream>>>(scb, vb + (size_t)b * KLEN * D,
                                                           avb + (size_t)b * NQ * D);
      }
      gemm(avb, sa_fcW + wo, yb, NB * NQ, D, D);
      k_ln<<<NB * NQ, 256, 0, stream>>>(xb, yb, sa_fcB + (size_t)l * D,
                                        ln1_g + (size_t)l * D, ln1_b + (size_t)l * D);
      gemm(xb,  ca_Wq + wo, qb, NB * NQ, D, D);
      gemm(enc, ca_Wk + wo, kb, NB * NE, D, D);
      gemm(enc, ca_Wv + wo, vb, NB * NE, D, D);
      for (int b = 0; b < NB; ++b) {
        const float* qB = qb + (size_t)b * NQ * D;
        dim3 gs(NE / 128, NQ / 128, NH);
        k_qkt<false><<<gs, 256, 0, stream>>>(qB, kb + (size_t)b * NE * D, nullptr, scb, NE);
        k_softmax<NE, false><<<dim3(NQ, NH), 256, 0, stream>>>(scb);
        k_pv<NE><<<dim3(NQ / 128, NH), 256, 0, stream>>>(scb, vb + (size_t)b * NE * D,
                                                         avb + (size_t)b * NQ * D);
      }
      gemm(avb, ca_fcW + wo, yb, NB * NQ, D, D);
      k_ln<<<NB * NQ, 256, 0, stream>>>(xb, yb, ca_fcB + (size_t)l * D,
                                        ln2_g + (size_t)l * D, ln2_b + (size_t)l * D);
      gemm(xb, ff_W1 + (size_t)l * D * DFF, hff, NB * NQ, DFF, D);
      k_bias_gelu<<<(NB * NQ * DFF) / 1024, 256, 0, stream>>>(hff, ff_b1 + (size_t)l * DFF);
      gemm(hff, ff_W2 + (size_t)l * DFF * D, yb, NB * NQ, D, DFF);
      k_ln<<<NB * NQ, 256, 0, stream>>>(xb, yb, ff_b2 + (size_t)l * D,
                                        ln3_g + (size_t)l * D, ln3_b + (size_t)l * D);
    }
    gemm(xb, out_W, out, NB * NQ, NV, D);
    return;
  }

  // ---------------- bf16x3 MFMA path ----------------
  auto asplit = [&](const float* A, int nelem) {
    k_split4<<<nelem / 1024, 256, 0, stream>>>(A, ah, al, nelem / 4);
  };
  auto wsplit = [&](const float* W, int K, int N) {
    k_split_t<<<dim3(N / 32, K / 32), 256, 0, stream>>>(W, bh, bl, K, N);
  };
  auto mgemm = [&](float* Cp, int Md, int Nd, int Kd,
                   const unsigned short* pah, const unsigned short* pal) {
    if (Nd >= 2048) {
      k_mgemm<128><<<dim3(Nd / 128, Md / 128), 256, 0, stream>>>(pah, pal, bh, bl, Cp, Md, Nd, Kd);
    } else {
      k_mgemm<64><<<dim3(Nd / 64, Md / 128), 256, 0, stream>>>(pah, pal, bh, bl, Cp, Md, Nd, Kd);
    }
  };

  k_embed<<<NB * NQ, 256, 0, stream>>>(emb, ids, xb);
  k_posemb<<<KLEN, 256, 0, stream>>>(r_emb);
  k_split4<<<(KLEN * D) / 1024, 256, 0, stream>>>(r_emb, rh, rl, (KLEN * D) / 4);
  k_split4<<<(NB * NE * D) / 1024, 256, 0, stream>>>(enc, ench, encl, (NB * NE * D) / 4);

  for (int l = 0; l < NL; ++l) {
    size_t wo = (size_t)l * D * D;
    // ---- self attention (TransformerXL relative) ----
    k_concat<<<NB * KLEN, 256, 0, stream>>>(mems + (size_t)l * NB * NM * D, xb, memb);
    asplit(xb, NB * NQ * D);
    wsplit(sa_Wq + wo, D, D);
    mgemm(qb, NB * NQ, D, D, ah, al);
    asplit(memb, NB * KLEN * D);
    wsplit(sa_Wk + wo, D, D);
    mgemm(kb, NB * KLEN, D, D, ah, al);
    wsplit(sa_Wv + wo, D, D);
    mgemm(vb, NB * KLEN, D, D, ah, al);
    wsplit(sa_Wr + wo, D, D);
    mgemm(rb, KLEN, D, D, rh, rl);
    if (tier2) {
      k_split4<<<(NB * NQ * D) / 1024, 256, 0, stream>>>(qb, qh, ql, (NB * NQ * D) / 4);
      k_split4<<<(NB * KLEN * D) / 1024, 256, 0, stream>>>(kb, kh, kl, (NB * KLEN * D) / 4);
      k_split4<<<(KLEN * D) / 1024, 256, 0, stream>>>(rb, rbh, rbl, (KLEN * D) / 4);
      for (int b = 0; b < NB; ++b)
        k_split_t<<<dim3(D / 32, KLEN / 32), 256, 0, stream>>>(
            vb + (size_t)b * KLEN * D, vth + (size_t)b * D * KLEN,
            vtl + (size_t)b * D * KLEN, KLEN, D);
      k_dotbias<<<dim3(NB * KLEN / 256, NH), 256, 0, stream>>>(u_b, kb, ukb, NB * KLEN);
      k_dotbias<<<dim3(KLEN / 256, NH), 256, 0, stream>>>(v_b, rb, vrb, KLEN);
      for (int b = 0; b < NB; ++b) {
        const unsigned short* qhB = qh + (size_t)b * NQ * D;
        const unsigned short* qlB = ql + (size_t)b * NQ * D;
        dim3 gs(KLEN / 128, NQ / 128, NH);
        k_mqkt<false><<<gs, 256, 0, stream>>>(qhB, qlB, kh + (size_t)b * KLEN * D,
                                              kl + (size_t)b * KLEN * D, scb, KLEN);
        k_mqkt<true><<<gs, 256, 0, stream>>>(qhB, qlB, rbh, rbl, scb, KLEN);
        k_softmax2<KLEN, true><<<dim3(NQ, NH), 256, 0, stream>>>(
            scb, ukb + (size_t)b * NH * KLEN, vrb, ph, pl);
        k_mpv<KLEN><<<dim3(NQ / 64, NH), 256, 0, stream>>>(
            ph, pl, vth + (size_t)b * D * KLEN, vtl + (size_t)b * D * KLEN,
            avb + (size_t)b * NQ * D);
      }
    } else {
      for (int b = 0; b < NB; ++b) {
        const float* qB = qb + (size_t)b * NQ * D;
        dim3 gs(KLEN / 128, NQ / 128, NH);
        k_qkt<false><<<gs, 256, 0, stream>>>(qB, kb + (size_t)b * KLEN * D, u_b, scb, KLEN);
        k_qkt<true><<<gs, 256, 0, stream>>>(qB, rb, v_b, scb, KLEN);
        k_softmax<KLEN, true><<<dim3(NQ, NH), 256, 0, stream>>>(scb);
        k_pv<KLEN><<<dim3(NQ / 128, NH), 256, 0, stream>>>(scb, vb + (size_t)b * KLEN * D,
                                                           avb + (size_t)b * NQ * D);
      }
    }
    asplit(avb, NB * NQ * D);
    wsplit(sa_fcW + wo, D, D);
    mgemm(yb, NB * NQ, D, D, ah, al);
    k_ln<<<NB * NQ, 256, 0, stream>>>(xb, yb, sa_fcB + (size_t)l * D,
                                      ln1_g + (size_t)l * D, ln1_b + (size_t)l * D);
    // ---- cross attention ----
    asplit(xb, NB * NQ * D);
    wsplit(ca_Wq + wo, D, D);
    mgemm(qb, NB * NQ, D, D, ah, al);
    wsplit(ca_Wk + wo, D, D);
    mgemm(kb, NB * NE, D, D, ench, encl);
    wsplit(ca_Wv + wo, D, D);
    mgemm(vb, NB * NE, D, D, ench, encl);
    if (tier2) {
      k_split4<<<(NB * NQ * D) / 1024, 256, 0, stream>>>(qb, qh, ql, (NB * NQ * D) / 4);
      k_split4<<<(NB * NE * D) / 1024, 256, 0, stream>>>(kb, kh, kl, (NB * NE * D) / 4);
      for (int b = 0; b < NB; ++b)
        k_split_t<<<dim3(D / 32, NE / 32), 256, 0, stream>>>(
            vb + (size_t)b * NE * D, vth + (size_t)b * D * NE,
            vtl + (size_t)b * D * NE, NE, D);
      for (int b = 0; b < NB; ++b) {
        const unsigned short* qhB = qh + (size_t)b * NQ * D;
        const unsigned short* qlB = ql + (size_t)b * NQ * D;
        dim3 gs(NE / 128, NQ / 128, NH);
        k_mqkt<false><<<gs, 256, 0, stream>>>(qhB, qlB, kh + (size_t)b * NE * D,
                                              kl + (size_t)b * NE * D, scb, NE);
        k_softmax2<NE, false><<<dim3(NQ, NH), 256, 0, stream>>>(scb, nullptr, nullptr, ph, pl);
        k_mpv<NE><<<dim3(NQ / 64, NH), 256, 0, stream>>>(
            ph, pl, vth + (size_t)b * D * NE, vtl + (size_t)b * D * NE,
            avb + (size_t)b * NQ * D);
      }
    } else {
      for (int b = 0; b < NB; ++b) {
        const float* qB = qb + (size_t)b * NQ * D;
        dim3 gs(NE / 128, NQ / 128, NH);
        k_qkt<false><<<gs, 256, 0, stream>>>(qB, kb + (size_t)b * NE * D, nullptr, scb, NE);
        k_softmax<NE, false><<<dim3(NQ, NH), 256, 0, stream>>>(scb);
        k_pv<NE><<<dim3(NQ / 128, NH), 256, 0, stream>>>(scb, vb + (size_t)b * NE * D,
                                                         avb + (size_t)b * NQ * D);
      }
    }
    asplit(avb, NB * NQ * D);
    wsplit(ca_fcW + wo, D, D);
    mgemm(yb, NB * NQ, D, D, ah, al);
    k_ln<<<NB * NQ, 256, 0, stream>>>(xb, yb, ca_fcB + (size_t)l * D,
                                      ln2_g + (size_t)l * D, ln2_b + (size_t)l * D);
    // ---- feed forward ----
    asplit(xb, NB * NQ * D);
    wsplit(ff_W1 + (size_t)l * D * DFF, D, DFF);
    mgemm(hff, NB * NQ, DFF, D, ah, al);
    k_bias_gelu<<<(NB * NQ * DFF) / 1024, 256, 0, stream>>>(hff, ff_b1 + (size_t)l * DFF);
    asplit(hff, NB * NQ * DFF);
    wsplit(ff_W2 + (size_t)l * DFF * D, DFF, D);
    mgemm(yb, NB * NQ, D, DFF, ah, al);
    k_ln<<<NB * NQ, 256, 0, stream>>>(xb, yb, ff_b2 + (size_t)l * D,
                                      ln3_g + (size_t)l * D, ln3_b + (size_t)l * D);
  }
  // ---- output projection ----
  asplit(xb, NB * NQ * D);
  wsplit(out_W, D, NV);
  mgemm(out, NB * NQ, NV, D, ah, al);
}